// Round 4
// baseline (210.663 us; speedup 1.0000x reference)
//
#include <hip/hip_runtime.h>
#include <math.h>

// Problem constants: B=4, C=64, H=128, W=128, K=9, O=64

typedef short v8s __attribute__((ext_vector_type(8)));
typedef float v4f __attribute__((ext_vector_type(4)));

__device__ __forceinline__ float fast_tanh(float a) {
    float aa = fabsf(a);
    float e = __expf(2.f * aa);
    float t = 1.f - 2.f / (e + 1.f);   // e==inf -> t = 1
    return copysignf(t, a);
}

// ---------------------------------------------------------------------------
// Kernel 0: prepack w_strip into bf16 A-fragment order.
// w_pack[(((k*4+wv)*2+kk)*64 + lane)*8 + j] = bf16( w[(o*64+c)*9+k] )
//   with o = wv*16 + (lane&15), c = kk*32 + (lane>>4)*8 + j.
// ---------------------------------------------------------------------------
__global__ __launch_bounds__(256) void k_pack(
    const float* __restrict__ w_strip, short* __restrict__ w_pack)
{
    int idx = blockIdx.x * 256 + threadIdx.x;
    int j    = idx & 7;
    int lane = (idx >> 3) & 63;
    int kk   = (idx >> 9) & 1;
    int wv   = (idx >> 10) & 3;
    int k    = idx >> 12;
    int c = (kk << 5) + ((lane >> 4) << 3) + j;
    int o = (wv << 4) + (lane & 15);
    union { short s; __bf16 h; } u;
    u.h = (__bf16)w_strip[(o * 64 + c) * 9 + k];
    w_pack[idx] = u.s;
}

// ---------------------------------------------------------------------------
// Kernel 0b: NCHW -> NHWC transpose of x. grid 1024 (b * 256 chunks of 64 px).
// ---------------------------------------------------------------------------
__global__ __launch_bounds__(256) void k_tr(
    const float* __restrict__ x, float* __restrict__ xt)
{
    __shared__ float l[64][65];
    const int t    = threadIdx.x;
    const int lane = t & 63;
    const int wv   = t >> 6;
    const int b    = blockIdx.x >> 8;
    const int pix0 = (blockIdx.x & 255) << 6;

#pragma unroll
    for (int it = 0; it < 16; ++it) {
        int c = (wv << 4) + it;
        l[lane][c] = x[(((size_t)(b << 6) + c) << 14) + pix0 + lane];
    }
    __syncthreads();
#pragma unroll
    for (int it = 0; it < 4; ++it) {
        int idx = (it << 8) + t;
        int p  = idx >> 4;
        int c4 = (idx & 15) << 2;
        float4 v = { l[p][c4], l[p][c4 + 1], l[p][c4 + 2], l[p][c4 + 3] };
        *(float4*)(xt + (((size_t)(b << 14) + pix0 + p) << 6) + c4) = v;
    }
}

// ---------------------------------------------------------------------------
// Kernel 1: fused 3x3 conv (off) + 5x5 conv (theta), channel-split 8-way,
// 2 channels per barrier round. grid (8,8,32): z = b*8+split. block 256.
// ---------------------------------------------------------------------------
__global__ __launch_bounds__(256, 8) void k_conv(
    const float* __restrict__ x,
    const float* __restrict__ w_off, const float* __restrict__ b_off,
    const float* __restrict__ w_th,  const float* __restrict__ b_th,
    float* __restrict__ off_raw, float* __restrict__ th_raw)
{
    __shared__ float tile[2][20][20];
    const int t  = threadIdx.x;
    const int tx = t & 15, ty = t >> 4;
    const int z  = blockIdx.z;
    const int b  = z >> 3, sp = z & 7;
    const int c0 = sp << 3;
    const int h0 = blockIdx.y << 4, w0 = blockIdx.x << 4;

    float accO[9], accT[9];
#pragma unroll
    for (int k = 0; k < 9; ++k) { accO[k] = 0.f; accT[k] = 0.f; }

    for (int rci = 0; rci < 4; ++rci) {
        __syncthreads();
        for (int e = t; e < 800; e += 256) {
            int ci2 = e >= 400;
            int ee = e - (ci2 ? 400 : 0);
            int r = ee / 20, cc = ee - r * 20;
            int hh = h0 + r - 2, ww = w0 + cc - 2;
            const float* xp = x + (((size_t)(b << 6) + c0 + (rci << 1) + ci2) << 14);
            tile[ci2][r][cc] = (hh >= 0 && hh < 128 && ww >= 0 && ww < 128)
                                 ? xp[(hh << 7) + ww] : 0.f;
        }
        __syncthreads();

#pragma unroll
        for (int ci2 = 0; ci2 < 2; ++ci2) {
            const int c = c0 + (rci << 1) + ci2;
            float win[5][5];
#pragma unroll
            for (int i = 0; i < 5; ++i)
#pragma unroll
                for (int j = 0; j < 5; ++j)
                    win[i][j] = tile[ci2][ty + i][tx + j];

#pragma unroll
            for (int k = 0; k < 9; ++k) {
                const float* wo = w_off + (size_t)((k << 6) + c) * 9;
                float a = accO[k];
#pragma unroll
                for (int i = 0; i < 3; ++i)
#pragma unroll
                    for (int j = 0; j < 3; ++j)
                        a = fmaf(win[i + 1][j + 1], wo[i * 3 + j], a);
                accO[k] = a;

                const float* wt = w_th + (size_t)((k << 6) + c) * 25;
                float bb = accT[k];
#pragma unroll
                for (int i = 0; i < 5; ++i)
#pragma unroll
                    for (int j = 0; j < 5; ++j)
                        bb = fmaf(win[i][j], wt[i * 5 + j], bb);
                accT[k] = bb;
            }
        }
    }

    const int pix = ((h0 + ty) << 7) + (w0 + tx);
#pragma unroll
    for (int k = 0; k < 9; ++k) {
        float vo = accO[k] + (sp == 0 ? b_off[k] : 0.f);
        float vt = accT[k] + (sp == 0 ? b_th[k]  : 0.f);
        atomicAdd(&off_raw[((b * 9 + k) << 14) + pix], vo);
        atomicAdd(&th_raw [((b * 9 + k) << 14) + pix], vt);
    }
}

// ---------------------------------------------------------------------------
// Kernel 1b: GN stats (sum, sumsq) per (b,k) for off and theta maps.
// ---------------------------------------------------------------------------
__global__ __launch_bounds__(256) void k_stats(
    const float* __restrict__ off_raw, const float* __restrict__ th_raw,
    float* __restrict__ stats)
{
    const int id  = blockIdx.x;          // 0..71
    const int arr = id >= 36;
    const int rem = id - arr * 36;       // b*9+k
    const float4* src = (const float4*)((arr ? th_raw : off_raw) + (rem << 14));

    float s1 = 0.f, s2 = 0.f;
    for (int i = threadIdx.x; i < 4096; i += 256) {
        float4 v = src[i];
        s1 += v.x + v.y + v.z + v.w;
        s2 += v.x * v.x + v.y * v.y + v.z * v.z + v.w * v.w;
    }
#pragma unroll
    for (int d = 32; d; d >>= 1) { s1 += __shfl_down(s1, d, 64); s2 += __shfl_down(s2, d, 64); }

    __shared__ float ls1[4], ls2[4];
    const int wv = threadIdx.x >> 6;
    if ((threadIdx.x & 63) == 0) { ls1[wv] = s1; ls2[wv] = s2; }
    __syncthreads();
    if (threadIdx.x == 0) {
        stats[arr * 72 + rem]      = ls1[0] + ls1[1] + ls1[2] + ls1[3];
        stats[arr * 72 + 36 + rem] = ls2[0] + ls2[1] + ls2[2] + ls2[3];
    }
}

// ---------------------------------------------------------------------------
// Kernel 2 (NEW): NHWC gather + MFMA strip contraction.
// grid 2048 (B * 512 chunks of 32 px), block 256 (4 waves), XCD swizzle.
// Lane: pixel = lane&31, channel-half = lane>>5 (8 ch per lane).
// LDS: bf16, [c-block(8)][pixel(32)] of 16B chunks, double-buffered; one
// barrier per k. Wave wv: A = w rows o in [wv*16, wv*16+16), all 32 pixels.
// ---------------------------------------------------------------------------
__global__ __launch_bounds__(256, 8) void k_sample_strip2(
    const float* __restrict__ xt,
    const float* __restrict__ off_raw, const float* __restrict__ th_raw,
    const float* __restrict__ stats,
    const float* __restrict__ g_off, const float* __restrict__ be_off,
    const float* __restrict__ g_th,  const float* __restrict__ be_th,
    const short* __restrict__ w_pack, const float* __restrict__ b_strip,
    float* __restrict__ out)
{
    __shared__ __align__(16) short smem[2][2048];
    const int t    = threadIdx.x;
    const int lane = t & 63;
    const int wv   = __builtin_amdgcn_readfirstlane(t >> 6);
    const int bid  = blockIdx.x;
    const int blk  = ((bid & 7) << 8) + (bid >> 3);   // XCD-chunked swizzle
    const int b    = blk >> 9;
    const int pix0 = (blk & 511) << 5;
    const int l32  = lane & 31;
    const int q    = lane >> 5;
    const int p_img = pix0 + l32;
    const int h    = p_img >> 7, w = p_img & 127;
    const int i15  = lane & 15, lg = lane >> 4;
    const int c0   = (wv << 4) + (q << 3);
    const int cb   = (wv << 1) + q;

    float muO[3], isO[3], muT[3], isT[3];
    const float inv_cnt = 1.f / (3.f * 16384.f);
#pragma unroll
    for (int g = 0; g < 3; ++g) {
        float s = 0.f, qq = 0.f;
#pragma unroll
        for (int j = 0; j < 3; ++j) { s += stats[b * 9 + 3 * g + j]; qq += stats[36 + b * 9 + 3 * g + j]; }
        float mu = s * inv_cnt;
        muO[g] = mu; isO[g] = rsqrtf(fmaxf(qq * inv_cnt - mu * mu, 0.f) + 1e-5f);
        s = 0.f; qq = 0.f;
#pragma unroll
        for (int j = 0; j < 3; ++j) { s += stats[72 + b * 9 + 3 * g + j]; qq += stats[108 + b * 9 + 3 * g + j]; }
        mu = s * inv_cnt;
        muT[g] = mu; isT[g] = rsqrtf(fmaxf(qq * inv_cnt - mu * mu, 0.f) + 1e-5f);
    }

    const float* xtb = xt + ((size_t)(b << 14) << 6);

    v4f acc[2];
    acc[0] = (v4f)0.f; acc[1] = (v4f)0.f;
    int cur = 0;

    for (int k = 0; k < 9; ++k) {
        float vv[8];
        if (k == 4) {
            const float* src = xtb + ((size_t)p_img << 6) + c0;
            float4 A = *(const float4*)src;
            float4 Bv = *(const float4*)(src + 4);
            vv[0] = A.x;  vv[1] = A.y;  vv[2] = A.z;  vv[3] = A.w;
            vv[4] = Bv.x; vv[5] = Bv.y; vv[6] = Bv.z; vv[7] = Bv.w;
        } else {
            const int s = k - 4;
            const int m = 4 + (s < 0 ? -s : s);
            const int g = m / 3;
            float z = (th_raw[((b * 9 + m) << 14) + p_img] - muT[g]) * isT[g] * g_th[m] + be_th[m];
            float f = fast_tanh((off_raw[((b * 9 + m) << 14) + p_img] - muO[g]) * isO[g] * g_off[m] + be_off[m]);
            float r = rsqrtf(1.f + z * z);     // cos(arctan z); sin = z*r; tan = z
            float fs = (float)s;
            float yy = (float)h + fs + fs * z + f * r;
            float xx = (float)w + fs + fs - z * r * f;
            yy = fminf(fmaxf(yy, 0.f), 127.f);
            xx = fminf(fmaxf(xx, 0.f), 127.f);
            int y0 = min((int)yy, 126);
            int x0 = min((int)xx, 126);
            float wy = yy - (float)y0;
            float wx = xx - (float)x0;
            const float* base = xtb + ((size_t)((y0 << 7) + x0) << 6) + c0;
#pragma unroll
            for (int hf = 0; hf < 2; ++hf) {
                const float* bp = base + (hf << 2);
                float4 c00 = *(const float4*)bp;
                float4 c01 = *(const float4*)(bp + 64);
                float4 c10 = *(const float4*)(bp + 8192);
                float4 c11 = *(const float4*)(bp + 8256);
                float tx0 = fmaf(wx, c01.x - c00.x, c00.x);
                float ty0 = fmaf(wx, c01.y - c00.y, c00.y);
                float tz0 = fmaf(wx, c01.z - c00.z, c00.z);
                float tw0 = fmaf(wx, c01.w - c00.w, c00.w);
                float bx0 = fmaf(wx, c11.x - c10.x, c10.x);
                float by0 = fmaf(wx, c11.y - c10.y, c10.y);
                float bz0 = fmaf(wx, c11.z - c10.z, c10.z);
                float bw0 = fmaf(wx, c11.w - c10.w, c10.w);
                vv[hf * 4 + 0] = fmaf(wy, bx0 - tx0, tx0);
                vv[hf * 4 + 1] = fmaf(wy, by0 - ty0, ty0);
                vv[hf * 4 + 2] = fmaf(wy, bz0 - tz0, tz0);
                vv[hf * 4 + 3] = fmaf(wy, bw0 - tw0, tw0);
            }
        }

        union { v8s s8; __bf16 hh[8]; } u;
#pragma unroll
        for (int j = 0; j < 8; ++j) u.hh[j] = (__bf16)vv[j];
        *(v8s*)&smem[cur][((cb << 5) + l32) << 3] = u.s8;
        __syncthreads();

        const short* wpk = w_pack + (((k << 2) + wv) << 10) + (lane << 3);
        v8s a0 = *(const v8s*)wpk;
        v8s a1 = *(const v8s*)(wpk + 512);

#pragma unroll
        for (int n = 0; n < 2; ++n) {
            int p16 = (n << 4) + i15;
            v8s b0 = *(const v8s*)&smem[cur][((lg << 5) + p16) << 3];
            v8s b1 = *(const v8s*)&smem[cur][(((lg + 4) << 5) + p16) << 3];
            acc[n] = __builtin_amdgcn_mfma_f32_16x16x32_bf16(a0, b0, acc[n], 0, 0, 0);
            acc[n] = __builtin_amdgcn_mfma_f32_16x16x32_bf16(a1, b1, acc[n], 0, 0, 0);
        }
        cur ^= 1;
    }

    // epilogue: D layout col=lane&15 (pixel), row=(lane>>4)*4+reg (o)
#pragma unroll
    for (int r = 0; r < 4; ++r) {
        int o = (wv << 4) + (lg << 2) + r;
        float bias = b_strip[o];
        float* op = out + (((size_t)(b << 6) + o) << 14) + pix0 + i15;
#pragma unroll
        for (int n = 0; n < 2; ++n)
            op[n << 4] = acc[n][r] + bias;
    }
}

// ---------------------------------------------------------------------------
// Kernel 2 (OLD fallback, NCHW gather): used when ws_size can't hold xt.
// ---------------------------------------------------------------------------
__global__ __launch_bounds__(256) void k_sample_strip_old(
    const float* __restrict__ x,
    const float* __restrict__ off_raw, const float* __restrict__ th_raw,
    const float* __restrict__ stats,
    const float* __restrict__ g_off, const float* __restrict__ be_off,
    const float* __restrict__ g_th,  const float* __restrict__ be_th,
    const short* __restrict__ w_pack, const float* __restrict__ b_strip,
    float* __restrict__ out)
{
    __shared__ __align__(16) short smem[64 * 64];
    const int t    = threadIdx.x;
    const int lane = t & 63;
    const int wv   = __builtin_amdgcn_readfirstlane(t >> 6);
    const int bid  = blockIdx.x;
    const int blk  = ((bid & 7) << 7) + (bid >> 3);
    const int b    = blk >> 8;
    const int pix0 = (blk & 255) << 6;
    const int p    = pix0 + lane;
    const int h    = p >> 7, w = p & 127;
    const int i15  = lane & 15, lg = lane >> 4;

    float muO[3], isO[3], muT[3], isT[3];
    const float inv_cnt = 1.f / (3.f * 16384.f);
#pragma unroll
    for (int g = 0; g < 3; ++g) {
        float s = 0.f, q = 0.f;
#pragma unroll
        for (int j = 0; j < 3; ++j) { s += stats[b * 9 + 3 * g + j]; q += stats[36 + b * 9 + 3 * g + j]; }
        float mu = s * inv_cnt;
        muO[g] = mu; isO[g] = rsqrtf(fmaxf(q * inv_cnt - mu * mu, 0.f) + 1e-5f);
        s = 0.f; q = 0.f;
#pragma unroll
        for (int j = 0; j < 3; ++j) { s += stats[72 + b * 9 + 3 * g + j]; q += stats[108 + b * 9 + 3 * g + j]; }
        mu = s * inv_cnt;
        muT[g] = mu; isT[g] = rsqrtf(fmaxf(q * inv_cnt - mu * mu, 0.f) + 1e-5f);
    }

    const float* xb = x + ((size_t)((b << 6) + (wv << 4)) << 14);
    v4f acc[4];
#pragma unroll
    for (int n = 0; n < 4; ++n) acc[n] = (v4f)0.f;

    for (int k = 0; k < 9; ++k) {
        float v[16];
        if (k == 4) {
#pragma unroll
            for (int ci = 0; ci < 16; ++ci) v[ci] = xb[(ci << 14) + p];
        } else {
            const int s = k - 4;
            const int m = 4 + (s < 0 ? -s : s);
            const int g = m / 3;
            float z = (th_raw[((b * 9 + m) << 14) + p] - muT[g]) * isT[g] * g_th[m] + be_th[m];
            float f = fast_tanh((off_raw[((b * 9 + m) << 14) + p] - muO[g]) * isO[g] * g_off[m] + be_off[m]);
            float r = rsqrtf(1.f + z * z);
            float fs = (float)s;
            float yy = (float)h + fs + fs * z + f * r;
            float xx = (float)w + fs + fs - z * r * f;
            yy = fminf(fmaxf(yy, 0.f), 127.f);
            xx = fminf(fmaxf(xx, 0.f), 127.f);
            int y0 = min((int)yy, 126);
            int x0 = min((int)xx, 126);
            float wy = yy - (float)y0;
            float wx = xx - (float)x0;
            const float* base = xb + (y0 << 7) + x0;
#pragma unroll
            for (int ci = 0; ci < 16; ++ci) {
                const float* qp = base + (ci << 14);
                float2 r0 = *(const float2*)qp;
                float2 r1 = *(const float2*)(qp + 128);
                float lo = fmaf(wx, r0.y - r0.x, r0.x);
                float hi = fmaf(wx, r1.y - r1.x, r1.x);
                v[ci] = fmaf(wy, hi - lo, lo);
            }
        }

        union { v8s s8; __bf16 hh[8]; } u0, u1;
#pragma unroll
        for (int ci = 0; ci < 8; ++ci) { u0.hh[ci] = (__bf16)v[ci]; u1.hh[ci] = (__bf16)v[ci + 8]; }
        *(v8s*)&smem[(lane << 6) + ((((wv << 1) + 0) + lane) & 7) * 8] = u0.s8;
        *(v8s*)&smem[(lane << 6) + ((((wv << 1) + 1) + lane) & 7) * 8] = u1.s8;
        __syncthreads();

        const short* wpk = w_pack + (((k << 2) + wv) << 10) + (lane << 3);
        v8s a0 = *(const v8s*)wpk;
        v8s a1 = *(const v8s*)(wpk + 512);

#pragma unroll
        for (int n = 0; n < 4; ++n) {
            int r = (n << 4) + i15;
            v8s b0 = *(const v8s*)&smem[(r << 6) + (((lg    ) + r) & 7) * 8];
            v8s b1 = *(const v8s*)&smem[(r << 6) + (((lg + 4) + r) & 7) * 8];
            acc[n] = __builtin_amdgcn_mfma_f32_16x16x32_bf16(a0, b0, acc[n], 0, 0, 0);
            acc[n] = __builtin_amdgcn_mfma_f32_16x16x32_bf16(a1, b1, acc[n], 0, 0, 0);
        }
        __syncthreads();
    }

#pragma unroll
    for (int r = 0; r < 4; ++r) {
        int o = (wv << 4) + (lg << 2) + r;
        float bias = b_strip[o];
        float* op = out + ((size_t)((b << 6) + o) << 14) + pix0 + i15;
#pragma unroll
        for (int n = 0; n < 4; ++n)
            op[n << 4] = acc[n][r] + bias;
    }
}

// ---------------------------------------------------------------------------
// Kernel 2b: output GN stats per (b,o). grid 256, block 256.
// ---------------------------------------------------------------------------
__global__ __launch_bounds__(256) void k_stats_out(
    const float* __restrict__ out, float* __restrict__ out_stats)
{
    const int bo = blockIdx.x;
    const float4* src = (const float4*)(out + ((size_t)bo << 14));
    float s1 = 0.f, s2 = 0.f;
    for (int i = threadIdx.x; i < 4096; i += 256) {
        float4 v = src[i];
        s1 += v.x + v.y + v.z + v.w;
        s2 += v.x * v.x + v.y * v.y + v.z * v.z + v.w * v.w;
    }
#pragma unroll
    for (int d = 32; d; d >>= 1) { s1 += __shfl_down(s1, d, 64); s2 += __shfl_down(s2, d, 64); }

    __shared__ float ls1[4], ls2[4];
    const int wv = threadIdx.x >> 6;
    if ((threadIdx.x & 63) == 0) { ls1[wv] = s1; ls2[wv] = s2; }
    __syncthreads();
    if (threadIdx.x == 0) {
        out_stats[bo]       = ls1[0] + ls1[1] + ls1[2] + ls1[3];
        out_stats[256 + bo] = ls2[0] + ls2[1] + ls2[2] + ls2[3];
    }
}

// ---------------------------------------------------------------------------
// Kernel 3: output GroupNorm (16 groups of 4 channels) + ReLU, in place.
// ---------------------------------------------------------------------------
__global__ __launch_bounds__(256) void k_gn_out(
    float* __restrict__ out, const float* __restrict__ out_stats,
    const float* __restrict__ gg, const float* __restrict__ gb)
{
    const float inv_cnt = 1.f / (4.f * 16384.f);
    const int n4 = 1 << 20;
    for (int idx = blockIdx.x * 256 + threadIdx.x; idx < n4; idx += gridDim.x * 256) {
        int flat = idx << 2;
        int ch = (flat >> 14) & 63;
        int b  = flat >> 20;
        int cb = (b << 6) + ((ch >> 2) << 2);
        float s = out_stats[cb] + out_stats[cb + 1] + out_stats[cb + 2] + out_stats[cb + 3];
        float q = out_stats[256 + cb] + out_stats[256 + cb + 1] + out_stats[256 + cb + 2] + out_stats[256 + cb + 3];
        float mu   = s * inv_cnt;
        float istd = rsqrtf(fmaxf(q * inv_cnt - mu * mu, 0.f) + 1e-5f);
        float ga = gg[ch] * istd;
        float be = gb[ch] - mu * ga;
        float4 v = *reinterpret_cast<float4*>(out + flat);
        v.x = fmaxf(fmaf(v.x, ga, be), 0.f);
        v.y = fmaxf(fmaf(v.y, ga, be), 0.f);
        v.z = fmaxf(fmaf(v.z, ga, be), 0.f);
        v.w = fmaxf(fmaf(v.w, ga, be), 0.f);
        *reinterpret_cast<float4*>(out + flat) = v;
    }
}

// ---------------------------------------------------------------------------
extern "C" void kernel_launch(void* const* d_in, const int* in_sizes, int n_in,
                              void* d_out, int out_size, void* d_ws, size_t ws_size,
                              hipStream_t stream)
{
    const float* x       = (const float*)d_in[0];
    const float* w_off   = (const float*)d_in[1];
    const float* b_off   = (const float*)d_in[2];
    const float* w_th    = (const float*)d_in[3];
    const float* b_th    = (const float*)d_in[4];
    const float* g_off   = (const float*)d_in[5];
    const float* be_off  = (const float*)d_in[6];
    const float* g_th    = (const float*)d_in[7];
    const float* be_th   = (const float*)d_in[8];
    const float* w_strip = (const float*)d_in[9];
    const float* b_strip = (const float*)d_in[10];
    const float* gg      = (const float*)d_in[11];
    const float* gb      = (const float*)d_in[12];

    float* out       = (float*)d_out;
    float* ws        = (float*)d_ws;
    float* off_raw   = ws;                      // 589824 floats
    float* th_raw    = ws + 589824;             // 589824 floats
    float* stats     = ws + 1179648;            // 144 floats
    float* out_stats = ws + 1179792;            // 512 floats
    short* w_pack    = (short*)(ws + 1180304);  // 36864 shorts = 18432 floats
    float* xt        = ws + 1198736;            // 4194304 floats (NHWC x)

    const size_t need_full = (size_t)(1198736 + 4194304) * sizeof(float);
    const bool big = ws_size >= need_full;

    // zero the atomic accumulation targets
    hipMemsetAsync(ws, 0, (size_t)1179648 * sizeof(float), stream);

    k_pack<<<144, 256, 0, stream>>>(w_strip, w_pack);
    if (big) k_tr<<<1024, 256, 0, stream>>>(x, xt);
    dim3 g1(8, 8, 32);
    k_conv<<<g1, 256, 0, stream>>>(x, w_off, b_off, w_th, b_th, off_raw, th_raw);
    k_stats<<<72, 256, 0, stream>>>(off_raw, th_raw, stats);
    if (big) {
        k_sample_strip2<<<2048, 256, 0, stream>>>(xt, off_raw, th_raw, stats,
                                                  g_off, be_off, g_th, be_th,
                                                  w_pack, b_strip, out);
    } else {
        k_sample_strip_old<<<1024, 256, 0, stream>>>(x, off_raw, th_raw, stats,
                                                     g_off, be_off, g_th, be_th,
                                                     w_pack, b_strip, out);
    }
    k_stats_out<<<256, 256, 0, stream>>>(out, out_stats);
    k_gn_out<<<2048, 256, 0, stream>>>(out, out_stats, gg, gb);
}

// Round 5
// 192.313 us; speedup vs baseline: 1.0954x; 1.0954x over previous
//
#include <hip/hip_runtime.h>
#include <math.h>

// Problem constants: B=4, C=64, H=128, W=128, K=9, O=64

typedef short v8s __attribute__((ext_vector_type(8)));
typedef float v4f __attribute__((ext_vector_type(4)));

__device__ __forceinline__ float fast_tanh(float a) {
    float aa = fabsf(a);
    float e = __expf(2.f * aa);
    float t = 1.f - 2.f / (e + 1.f);   // e==inf -> t = 1
    return copysignf(t, a);
}

// ---------------------------------------------------------------------------
// Kernel 0: prepack w_strip into bf16 A-fragment order.
// w_pack[(((k*4+wv)*2+kk)*64 + lane)*8 + j] = bf16( w[(o*64+c)*9+k] )
//   with o = wv*16 + (lane&15), c = kk*32 + (lane>>4)*8 + j.
// ---------------------------------------------------------------------------
__global__ __launch_bounds__(256) void k_pack(
    const float* __restrict__ w_strip, short* __restrict__ w_pack)
{
    int idx = blockIdx.x * 256 + threadIdx.x;
    int j    = idx & 7;
    int lane = (idx >> 3) & 63;
    int kk   = (idx >> 9) & 1;
    int wv   = (idx >> 10) & 3;
    int k    = idx >> 12;
    int c = (kk << 5) + ((lane >> 4) << 3) + j;
    int o = (wv << 4) + (lane & 15);
    union { short s; __bf16 h; } u;
    u.h = (__bf16)w_strip[(o * 64 + c) * 9 + k];
    w_pack[idx] = u.s;
}

// ---------------------------------------------------------------------------
// Kernel 0b: NCHW -> NHWC transpose of x. grid 1024 (b * 256 chunks of 64 px).
// ---------------------------------------------------------------------------
__global__ __launch_bounds__(256) void k_tr(
    const float* __restrict__ x, float* __restrict__ xt)
{
    __shared__ float l[64][65];
    const int t    = threadIdx.x;
    const int lane = t & 63;
    const int wv   = t >> 6;
    const int b    = blockIdx.x >> 8;
    const int pix0 = (blockIdx.x & 255) << 6;

#pragma unroll
    for (int it = 0; it < 16; ++it) {
        int c = (wv << 4) + it;
        l[lane][c] = x[(((size_t)(b << 6) + c) << 14) + pix0 + lane];
    }
    __syncthreads();
#pragma unroll
    for (int it = 0; it < 4; ++it) {
        int idx = (it << 8) + t;
        int p  = idx >> 4;
        int c4 = (idx & 15) << 2;
        float4 v = { l[p][c4], l[p][c4 + 1], l[p][c4 + 2], l[p][c4 + 3] };
        *(float4*)(xt + (((size_t)(b << 14) + pix0 + p) << 6) + c4) = v;
    }
}

// ---------------------------------------------------------------------------
// Kernel 1: fused 3x3 conv (off) + 5x5 conv (theta), channel-split 8-way.
// Tile: 32 wide x 8 tall outputs; LDS tile[12][36] -> window reads are
// conflict-free (2 row-groups per wave, 36 banks apart => 2 lanes/bank).
// One channel per barrier round, wave-uniform SGPR base for staging.
// grid (4,16,32): z = b*8+split. block 256.
// ---------------------------------------------------------------------------
__global__ __launch_bounds__(256, 8) void k_conv(
    const float* __restrict__ x,
    const float* __restrict__ w_off, const float* __restrict__ b_off,
    const float* __restrict__ w_th,  const float* __restrict__ b_th,
    float* __restrict__ off_raw, float* __restrict__ th_raw)
{
    __shared__ float tile[12][36];
    const int t  = threadIdx.x;
    const int tx = t & 31, ty = t >> 5;
    const int z  = blockIdx.z;
    const int b  = z >> 3, sp = z & 7;
    const int c0 = sp << 3;
    const int h0 = blockIdx.y << 3, w0 = blockIdx.x << 5;

    float accO[9], accT[9];
#pragma unroll
    for (int k = 0; k < 9; ++k) { accO[k] = 0.f; accT[k] = 0.f; }

    for (int ci = 0; ci < 8; ++ci) {
        const int c = c0 + ci;
        __syncthreads();
        const float* xp = x + (((size_t)(b << 6) + c) << 14);   // uniform base
        for (int e = t; e < 432; e += 256) {
            int r = e / 36, cc = e - r * 36;
            int hh = h0 + r - 2, ww = w0 + cc - 2;
            tile[r][cc] = (hh >= 0 && hh < 128 && ww >= 0 && ww < 128)
                            ? xp[(hh << 7) + ww] : 0.f;
        }
        __syncthreads();

        float win[5][5];
#pragma unroll
        for (int i = 0; i < 5; ++i)
#pragma unroll
            for (int j = 0; j < 5; ++j)
                win[i][j] = tile[ty + i][tx + j];

#pragma unroll
        for (int k = 0; k < 9; ++k) {
            const float* wo = w_off + (size_t)((k << 6) + c) * 9;
            float a = accO[k];
#pragma unroll
            for (int i = 0; i < 3; ++i)
#pragma unroll
                for (int j = 0; j < 3; ++j)
                    a = fmaf(win[i + 1][j + 1], wo[i * 3 + j], a);
            accO[k] = a;

            const float* wt = w_th + (size_t)((k << 6) + c) * 25;
            float bb = accT[k];
#pragma unroll
            for (int i = 0; i < 5; ++i)
#pragma unroll
                for (int j = 0; j < 5; ++j)
                    bb = fmaf(win[i][j], wt[i * 5 + j], bb);
            accT[k] = bb;
        }
    }

    const int pix = ((h0 + ty) << 7) + (w0 + tx);
#pragma unroll
    for (int k = 0; k < 9; ++k) {
        float vo = accO[k] + (sp == 0 ? b_off[k] : 0.f);
        float vt = accT[k] + (sp == 0 ? b_th[k]  : 0.f);
        atomicAdd(&off_raw[((b * 9 + k) << 14) + pix], vo);
        atomicAdd(&th_raw [((b * 9 + k) << 14) + pix], vt);
    }
}

// ---------------------------------------------------------------------------
// Kernel 1b: GN stats (sum, sumsq) per (b,k) for off and theta maps.
// ---------------------------------------------------------------------------
__global__ __launch_bounds__(256) void k_stats(
    const float* __restrict__ off_raw, const float* __restrict__ th_raw,
    float* __restrict__ stats)
{
    const int id  = blockIdx.x;          // 0..71
    const int arr = id >= 36;
    const int rem = id - arr * 36;       // b*9+k
    const float4* src = (const float4*)((arr ? th_raw : off_raw) + (rem << 14));

    float s1 = 0.f, s2 = 0.f;
    for (int i = threadIdx.x; i < 4096; i += 256) {
        float4 v = src[i];
        s1 += v.x + v.y + v.z + v.w;
        s2 += v.x * v.x + v.y * v.y + v.z * v.z + v.w * v.w;
    }
#pragma unroll
    for (int d = 32; d; d >>= 1) { s1 += __shfl_down(s1, d, 64); s2 += __shfl_down(s2, d, 64); }

    __shared__ float ls1[4], ls2[4];
    const int wv = threadIdx.x >> 6;
    if ((threadIdx.x & 63) == 0) { ls1[wv] = s1; ls2[wv] = s2; }
    __syncthreads();
    if (threadIdx.x == 0) {
        stats[arr * 72 + rem]      = ls1[0] + ls1[1] + ls1[2] + ls1[3];
        stats[arr * 72 + 36 + rem] = ls2[0] + ls2[1] + ls2[2] + ls2[3];
    }
}

// ---------------------------------------------------------------------------
// Kernel 2: NHWC gather + MFMA strip contraction + fused output-GN stats.
// grid 2048 (B * 512 chunks of 32 px), block 256 (4 waves), XCD swizzle.
// ---------------------------------------------------------------------------
__global__ __launch_bounds__(256, 8) void k_sample_strip2(
    const float* __restrict__ xt,
    const float* __restrict__ off_raw, const float* __restrict__ th_raw,
    const float* __restrict__ stats,
    const float* __restrict__ g_off, const float* __restrict__ be_off,
    const float* __restrict__ g_th,  const float* __restrict__ be_th,
    const short* __restrict__ w_pack, const float* __restrict__ b_strip,
    float* __restrict__ out, float* __restrict__ out_stats)
{
    __shared__ __align__(16) short smem[2][2048];
    const int t    = threadIdx.x;
    const int lane = t & 63;
    const int wv   = __builtin_amdgcn_readfirstlane(t >> 6);
    const int bid  = blockIdx.x;
    const int blk  = ((bid & 7) << 8) + (bid >> 3);   // XCD-chunked swizzle
    const int b    = blk >> 9;
    const int pix0 = (blk & 511) << 5;
    const int l32  = lane & 31;
    const int q    = lane >> 5;
    const int p_img = pix0 + l32;
    const int h    = p_img >> 7, w = p_img & 127;
    const int i15  = lane & 15, lg = lane >> 4;
    const int c0   = (wv << 4) + (q << 3);
    const int cb   = (wv << 1) + q;

    float muO[3], isO[3], muT[3], isT[3];
    const float inv_cnt = 1.f / (3.f * 16384.f);
#pragma unroll
    for (int g = 0; g < 3; ++g) {
        float s = 0.f, qq = 0.f;
#pragma unroll
        for (int j = 0; j < 3; ++j) { s += stats[b * 9 + 3 * g + j]; qq += stats[36 + b * 9 + 3 * g + j]; }
        float mu = s * inv_cnt;
        muO[g] = mu; isO[g] = rsqrtf(fmaxf(qq * inv_cnt - mu * mu, 0.f) + 1e-5f);
        s = 0.f; qq = 0.f;
#pragma unroll
        for (int j = 0; j < 3; ++j) { s += stats[72 + b * 9 + 3 * g + j]; qq += stats[108 + b * 9 + 3 * g + j]; }
        mu = s * inv_cnt;
        muT[g] = mu; isT[g] = rsqrtf(fmaxf(qq * inv_cnt - mu * mu, 0.f) + 1e-5f);
    }

    const float* xtb = xt + ((size_t)(b << 14) << 6);

    v4f acc[2];
    acc[0] = (v4f)0.f; acc[1] = (v4f)0.f;
    int cur = 0;

    for (int k = 0; k < 9; ++k) {
        float vv[8];
        if (k == 4) {
            const float* src = xtb + ((size_t)p_img << 6) + c0;
            float4 A = *(const float4*)src;
            float4 Bv = *(const float4*)(src + 4);
            vv[0] = A.x;  vv[1] = A.y;  vv[2] = A.z;  vv[3] = A.w;
            vv[4] = Bv.x; vv[5] = Bv.y; vv[6] = Bv.z; vv[7] = Bv.w;
        } else {
            const int s = k - 4;
            const int m = 4 + (s < 0 ? -s : s);
            const int g = m / 3;
            float z = (th_raw[((b * 9 + m) << 14) + p_img] - muT[g]) * isT[g] * g_th[m] + be_th[m];
            float f = fast_tanh((off_raw[((b * 9 + m) << 14) + p_img] - muO[g]) * isO[g] * g_off[m] + be_off[m]);
            float r = rsqrtf(1.f + z * z);     // cos(arctan z); sin = z*r; tan = z
            float fs = (float)s;
            float yy = (float)h + fs + fs * z + f * r;
            float xx = (float)w + fs + fs - z * r * f;
            yy = fminf(fmaxf(yy, 0.f), 127.f);
            xx = fminf(fmaxf(xx, 0.f), 127.f);
            int y0 = min((int)yy, 126);
            int x0 = min((int)xx, 126);
            float wy = yy - (float)y0;
            float wx = xx - (float)x0;
            const float* base = xtb + ((size_t)((y0 << 7) + x0) << 6) + c0;
#pragma unroll
            for (int hf = 0; hf < 2; ++hf) {
                const float* bp = base + (hf << 2);
                float4 c00 = *(const float4*)bp;
                float4 c01 = *(const float4*)(bp + 64);
                float4 c10 = *(const float4*)(bp + 8192);
                float4 c11 = *(const float4*)(bp + 8256);
                float tx0 = fmaf(wx, c01.x - c00.x, c00.x);
                float ty0 = fmaf(wx, c01.y - c00.y, c00.y);
                float tz0 = fmaf(wx, c01.z - c00.z, c00.z);
                float tw0 = fmaf(wx, c01.w - c00.w, c00.w);
                float bx0 = fmaf(wx, c11.x - c10.x, c10.x);
                float by0 = fmaf(wx, c11.y - c10.y, c10.y);
                float bz0 = fmaf(wx, c11.z - c10.z, c10.z);
                float bw0 = fmaf(wx, c11.w - c10.w, c10.w);
                vv[hf * 4 + 0] = fmaf(wy, bx0 - tx0, tx0);
                vv[hf * 4 + 1] = fmaf(wy, by0 - ty0, ty0);
                vv[hf * 4 + 2] = fmaf(wy, bz0 - tz0, tz0);
                vv[hf * 4 + 3] = fmaf(wy, bw0 - tw0, tw0);
            }
        }

        union { v8s s8; __bf16 hh[8]; } u;
#pragma unroll
        for (int j = 0; j < 8; ++j) u.hh[j] = (__bf16)vv[j];
        *(v8s*)&smem[cur][((cb << 5) + l32) << 3] = u.s8;
        __syncthreads();

        const short* wpk = w_pack + (((k << 2) + wv) << 10) + (lane << 3);
        v8s a0 = *(const v8s*)wpk;
        v8s a1 = *(const v8s*)(wpk + 512);

#pragma unroll
        for (int n = 0; n < 2; ++n) {
            int p16 = (n << 4) + i15;
            v8s b0 = *(const v8s*)&smem[cur][((lg << 5) + p16) << 3];
            v8s b1 = *(const v8s*)&smem[cur][(((lg + 4) << 5) + p16) << 3];
            acc[n] = __builtin_amdgcn_mfma_f32_16x16x32_bf16(a0, b0, acc[n], 0, 0, 0);
            acc[n] = __builtin_amdgcn_mfma_f32_16x16x32_bf16(a1, b1, acc[n], 0, 0, 0);
        }
        cur ^= 1;
    }

    // epilogue: D layout col=lane&15 (pixel), row=(lane>>4)*4+reg (o)
    // + fused output GN stats (reduce over the 16 pixel-lanes and n)
#pragma unroll
    for (int r = 0; r < 4; ++r) {
        int o = (wv << 4) + (lg << 2) + r;
        float bias = b_strip[o];
        float v0 = acc[0][r] + bias;
        float v1 = acc[1][r] + bias;
        float* op = out + (((size_t)(b << 6) + o) << 14) + pix0 + i15;
        op[0]  = v0;
        op[16] = v1;
        float s1 = v0 + v1;
        float s2 = v0 * v0 + v1 * v1;
#pragma unroll
        for (int d = 1; d <= 8; d <<= 1) {
            s1 += __shfl_xor(s1, d, 64);
            s2 += __shfl_xor(s2, d, 64);
        }
        if (i15 == 0) {
            atomicAdd(&out_stats[(b << 6) + o], s1);
            atomicAdd(&out_stats[256 + (b << 6) + o], s2);
        }
    }
}

// ---------------------------------------------------------------------------
// Kernel 2 (OLD fallback, NCHW gather): used when ws_size can't hold xt.
// ---------------------------------------------------------------------------
__global__ __launch_bounds__(256) void k_sample_strip_old(
    const float* __restrict__ x,
    const float* __restrict__ off_raw, const float* __restrict__ th_raw,
    const float* __restrict__ stats,
    const float* __restrict__ g_off, const float* __restrict__ be_off,
    const float* __restrict__ g_th,  const float* __restrict__ be_th,
    const short* __restrict__ w_pack, const float* __restrict__ b_strip,
    float* __restrict__ out)
{
    __shared__ __align__(16) short smem[64 * 64];
    const int t    = threadIdx.x;
    const int lane = t & 63;
    const int wv   = __builtin_amdgcn_readfirstlane(t >> 6);
    const int bid  = blockIdx.x;
    const int blk  = ((bid & 7) << 7) + (bid >> 3);
    const int b    = blk >> 8;
    const int pix0 = (blk & 255) << 6;
    const int p    = pix0 + lane;
    const int h    = p >> 7, w = p & 127;
    const int i15  = lane & 15, lg = lane >> 4;

    float muO[3], isO[3], muT[3], isT[3];
    const float inv_cnt = 1.f / (3.f * 16384.f);
#pragma unroll
    for (int g = 0; g < 3; ++g) {
        float s = 0.f, q = 0.f;
#pragma unroll
        for (int j = 0; j < 3; ++j) { s += stats[b * 9 + 3 * g + j]; q += stats[36 + b * 9 + 3 * g + j]; }
        float mu = s * inv_cnt;
        muO[g] = mu; isO[g] = rsqrtf(fmaxf(q * inv_cnt - mu * mu, 0.f) + 1e-5f);
        s = 0.f; q = 0.f;
#pragma unroll
        for (int j = 0; j < 3; ++j) { s += stats[72 + b * 9 + 3 * g + j]; q += stats[108 + b * 9 + 3 * g + j]; }
        mu = s * inv_cnt;
        muT[g] = mu; isT[g] = rsqrtf(fmaxf(q * inv_cnt - mu * mu, 0.f) + 1e-5f);
    }

    const float* xb = x + ((size_t)((b << 6) + (wv << 4)) << 14);
    v4f acc[4];
#pragma unroll
    for (int n = 0; n < 4; ++n) acc[n] = (v4f)0.f;

    for (int k = 0; k < 9; ++k) {
        float v[16];
        if (k == 4) {
#pragma unroll
            for (int ci = 0; ci < 16; ++ci) v[ci] = xb[(ci << 14) + p];
        } else {
            const int s = k - 4;
            const int m = 4 + (s < 0 ? -s : s);
            const int g = m / 3;
            float z = (th_raw[((b * 9 + m) << 14) + p] - muT[g]) * isT[g] * g_th[m] + be_th[m];
            float f = fast_tanh((off_raw[((b * 9 + m) << 14) + p] - muO[g]) * isO[g] * g_off[m] + be_off[m]);
            float r = rsqrtf(1.f + z * z);
            float fs = (float)s;
            float yy = (float)h + fs + fs * z + f * r;
            float xx = (float)w + fs + fs - z * r * f;
            yy = fminf(fmaxf(yy, 0.f), 127.f);
            xx = fminf(fmaxf(xx, 0.f), 127.f);
            int y0 = min((int)yy, 126);
            int x0 = min((int)xx, 126);
            float wy = yy - (float)y0;
            float wx = xx - (float)x0;
            const float* base = xb + (y0 << 7) + x0;
#pragma unroll
            for (int ci = 0; ci < 16; ++ci) {
                const float* qp = base + (ci << 14);
                float2 r0 = *(const float2*)qp;
                float2 r1 = *(const float2*)(qp + 128);
                float lo = fmaf(wx, r0.y - r0.x, r0.x);
                float hi = fmaf(wx, r1.y - r1.x, r1.x);
                v[ci] = fmaf(wy, hi - lo, lo);
            }
        }

        union { v8s s8; __bf16 hh[8]; } u0, u1;
#pragma unroll
        for (int ci = 0; ci < 8; ++ci) { u0.hh[ci] = (__bf16)v[ci]; u1.hh[ci] = (__bf16)v[ci + 8]; }
        *(v8s*)&smem[(lane << 6) + ((((wv << 1) + 0) + lane) & 7) * 8] = u0.s8;
        *(v8s*)&smem[(lane << 6) + ((((wv << 1) + 1) + lane) & 7) * 8] = u1.s8;
        __syncthreads();

        const short* wpk = w_pack + (((k << 2) + wv) << 10) + (lane << 3);
        v8s a0 = *(const v8s*)wpk;
        v8s a1 = *(const v8s*)(wpk + 512);

#pragma unroll
        for (int n = 0; n < 4; ++n) {
            int r = (n << 4) + i15;
            v8s b0 = *(const v8s*)&smem[(r << 6) + (((lg    ) + r) & 7) * 8];
            v8s b1 = *(const v8s*)&smem[(r << 6) + (((lg + 4) + r) & 7) * 8];
            acc[n] = __builtin_amdgcn_mfma_f32_16x16x32_bf16(a0, b0, acc[n], 0, 0, 0);
            acc[n] = __builtin_amdgcn_mfma_f32_16x16x32_bf16(a1, b1, acc[n], 0, 0, 0);
        }
        __syncthreads();
    }

#pragma unroll
    for (int r = 0; r < 4; ++r) {
        int o = (wv << 4) + (lg << 2) + r;
        float bias = b_strip[o];
        float* op = out + ((size_t)((b << 6) + o) << 14) + pix0 + i15;
#pragma unroll
        for (int n = 0; n < 4; ++n)
            op[n << 4] = acc[n][r] + bias;
    }
}

// ---------------------------------------------------------------------------
// Kernel 2b: output GN stats per (b,o). grid 256. (fallback path only)
// ---------------------------------------------------------------------------
__global__ __launch_bounds__(256) void k_stats_out(
    const float* __restrict__ out, float* __restrict__ out_stats)
{
    const int bo = blockIdx.x;
    const float4* src = (const float4*)(out + ((size_t)bo << 14));
    float s1 = 0.f, s2 = 0.f;
    for (int i = threadIdx.x; i < 4096; i += 256) {
        float4 v = src[i];
        s1 += v.x + v.y + v.z + v.w;
        s2 += v.x * v.x + v.y * v.y + v.z * v.z + v.w * v.w;
    }
#pragma unroll
    for (int d = 32; d; d >>= 1) { s1 += __shfl_down(s1, d, 64); s2 += __shfl_down(s2, d, 64); }

    __shared__ float ls1[4], ls2[4];
    const int wv = threadIdx.x >> 6;
    if ((threadIdx.x & 63) == 0) { ls1[wv] = s1; ls2[wv] = s2; }
    __syncthreads();
    if (threadIdx.x == 0) {
        out_stats[bo]       = ls1[0] + ls1[1] + ls1[2] + ls1[3];
        out_stats[256 + bo] = ls2[0] + ls2[1] + ls2[2] + ls2[3];
    }
}

// ---------------------------------------------------------------------------
// Kernel 3: output GroupNorm (16 groups of 4 channels) + ReLU, in place.
// ---------------------------------------------------------------------------
__global__ __launch_bounds__(256) void k_gn_out(
    float* __restrict__ out, const float* __restrict__ out_stats,
    const float* __restrict__ gg, const float* __restrict__ gb)
{
    const float inv_cnt = 1.f / (4.f * 16384.f);
    const int n4 = 1 << 20;
    for (int idx = blockIdx.x * 256 + threadIdx.x; idx < n4; idx += gridDim.x * 256) {
        int flat = idx << 2;
        int ch = (flat >> 14) & 63;
        int b  = flat >> 20;
        int cb = (b << 6) + ((ch >> 2) << 2);
        float s = out_stats[cb] + out_stats[cb + 1] + out_stats[cb + 2] + out_stats[cb + 3];
        float q = out_stats[256 + cb] + out_stats[256 + cb + 1] + out_stats[256 + cb + 2] + out_stats[256 + cb + 3];
        float mu   = s * inv_cnt;
        float istd = rsqrtf(fmaxf(q * inv_cnt - mu * mu, 0.f) + 1e-5f);
        float ga = gg[ch] * istd;
        float be = gb[ch] - mu * ga;
        float4 v = *reinterpret_cast<float4*>(out + flat);
        v.x = fmaxf(fmaf(v.x, ga, be), 0.f);
        v.y = fmaxf(fmaf(v.y, ga, be), 0.f);
        v.z = fmaxf(fmaf(v.z, ga, be), 0.f);
        v.w = fmaxf(fmaf(v.w, ga, be), 0.f);
        *reinterpret_cast<float4*>(out + flat) = v;
    }
}

// ---------------------------------------------------------------------------
extern "C" void kernel_launch(void* const* d_in, const int* in_sizes, int n_in,
                              void* d_out, int out_size, void* d_ws, size_t ws_size,
                              hipStream_t stream)
{
    const float* x       = (const float*)d_in[0];
    const float* w_off   = (const float*)d_in[1];
    const float* b_off   = (const float*)d_in[2];
    const float* w_th    = (const float*)d_in[3];
    const float* b_th    = (const float*)d_in[4];
    const float* g_off   = (const float*)d_in[5];
    const float* be_off  = (const float*)d_in[6];
    const float* g_th    = (const float*)d_in[7];
    const float* be_th   = (const float*)d_in[8];
    const float* w_strip = (const float*)d_in[9];
    const float* b_strip = (const float*)d_in[10];
    const float* gg      = (const float*)d_in[11];
    const float* gb      = (const float*)d_in[12];

    float* out       = (float*)d_out;
    float* ws        = (float*)d_ws;
    float* off_raw   = ws;                      // 589824 floats
    float* th_raw    = ws + 589824;             // 589824 floats
    float* stats     = ws + 1179648;            // 144 floats
    float* out_stats = ws + 1179792;            // 512 floats
    short* w_pack    = (short*)(ws + 1180304);  // 36864 shorts = 18432 floats
    float* xt        = ws + 1198736;            // 4194304 floats (NHWC x)

    const size_t need_full = (size_t)(1198736 + 4194304) * sizeof(float);
    const bool big = ws_size >= need_full;

    // zero atomic accumulation targets (off/th partials + stats + out_stats)
    hipMemsetAsync(ws, 0, (size_t)1180304 * sizeof(float), stream);

    k_pack<<<144, 256, 0, stream>>>(w_strip, w_pack);
    if (big) k_tr<<<1024, 256, 0, stream>>>(x, xt);
    dim3 g1(4, 16, 32);
    k_conv<<<g1, 256, 0, stream>>>(x, w_off, b_off, w_th, b_th, off_raw, th_raw);
    k_stats<<<72, 256, 0, stream>>>(off_raw, th_raw, stats);
    if (big) {
        k_sample_strip2<<<2048, 256, 0, stream>>>(xt, off_raw, th_raw, stats,
                                                  g_off, be_off, g_th, be_th,
                                                  w_pack, b_strip, out, out_stats);
    } else {
        k_sample_strip_old<<<1024, 256, 0, stream>>>(x, off_raw, th_raw, stats,
                                                     g_off, be_off, g_th, be_th,
                                                     w_pack, b_strip, out);
        k_stats_out<<<256, 256, 0, stream>>>(out, out_stats);
    }
    k_gn_out<<<4096, 256, 0, stream>>>(out, out_stats, gg, gb);
}